// Round 9
// baseline (113.567 us; speedup 1.0000x reference)
//
#include <hip/hip_runtime.h>
#include <math.h>

// B=32, HW=4096 (64x64), C=256, G=32, CG=8 -> 1024 samples of (8,64,64).
// r9: 512 blocks x 1024 threads; each block pipelines TWO quad-adjacent
// samples (s0,s1) with double LDS tiles (~148 KB, 1 block/CU, 16 waves).
// s1's global reads overlap stats(s0); stats(s1) overlaps s0's store drain.

#define NBLK 512
#define NTHR 1024
#define CSTR 2052   // u32 per channel (4104 bf16 = 4096 px + pad)

typedef unsigned int uint;

__device__ __forceinline__ uint pk2(float a, float b) {   // 2x f32 -> packed bf16
    uint ua = __builtin_bit_cast(uint, a);
    uint ub = __builtin_bit_cast(uint, b);
    return ((ua + 0x8000u) >> 16) | ((ub + 0x8000u) & 0xFFFF0000u);
}
__device__ __forceinline__ float blo(uint u) { return __builtin_bit_cast(float, u << 16); }
__device__ __forceinline__ float bhi(uint u) { return __builtin_bit_cast(float, u & 0xFFFF0000u); }
__device__ __forceinline__ float sigm(float v) { return 1.0f / (1.0f + __expf(-v)); }

// ---- stats phases (r5-proven 512-thread geometry; t>=512 waves idle) ------
__device__ __forceinline__ void stats_phases(
    const int t, const uint* __restrict__ tile,
    float* __restrict__ sg, float* __restrict__ t1s, float* __restrict__ weff,
    float* __restrict__ wconst, float* __restrict__ uni,
    float* Ti, float* m2s, float* Ai, float* Ci, float* x11s, float* x21s,
    const float* __restrict__ w1, const float* __restrict__ b1,
    const float* __restrict__ w3, const float* __restrict__ b3,
    const float* __restrict__ gn_w, const float* __restrict__ gn_b)
{
    float* Rs = uni;
    float* Cs = uni + 512;

    // P2: row/col sums + totals
    if (t < 512) {
        const int i = t >> 6, l = t & 63, ys = l >> 3, xb = l & 7;
        float col[8] = {0, 0, 0, 0, 0, 0, 0, 0};
        float rowv[8];
#pragma unroll
        for (int r = 0; r < 8; ++r) {
            const uint4 d = *reinterpret_cast<const uint4*>(
                &tile[i * CSTR + (ys * 8 + r) * 32 + xb * 4]);
            float f0 = blo(d.x), f1 = bhi(d.x), f2 = blo(d.y), f3 = bhi(d.y);
            float f4 = blo(d.z), f5 = bhi(d.z), f6 = blo(d.w), f7 = bhi(d.w);
            rowv[r] = ((f0 + f1) + (f2 + f3)) + ((f4 + f5) + (f6 + f7));
            col[0] += f0; col[1] += f1; col[2] += f2; col[3] += f3;
            col[4] += f4; col[5] += f5; col[6] += f6; col[7] += f7;
        }
#pragma unroll
        for (int r = 0; r < 8; ++r) {
            float v = rowv[r];
            v += __shfl_xor(v, 1); v += __shfl_xor(v, 2); v += __shfl_xor(v, 4);
            if (xb == 0) Rs[i * 64 + ys * 8 + r] = v;
        }
        float tot = 0.f;
#pragma unroll
        for (int j = 0; j < 8; ++j) {
            float c = col[j];
            c += __shfl_xor(c, 8); c += __shfl_xor(c, 16); c += __shfl_xor(c, 32);
            if (ys == 0) Cs[i * 64 + xb * 8 + j] = c;
            tot += c;
        }
        tot += __shfl_xor(tot, 1); tot += __shfl_xor(tot, 2); tot += __shfl_xor(tot, 4);
        if (l == 0) Ti[i] = tot;
    }
    __syncthreads();

    // P3: gate matmul + sigmoid
    if (t < 512) {
        const int o = t >> 6, p = t & 63;
        float vy = b1[o], vx = b1[o];
#pragma unroll
        for (int i = 0; i < 8; ++i) {
            float wv = w1[o * 8 + i] * (1.0f / 64.0f);
            vy += wv * Rs[i * 64 + p];
            vx += wv * Cs[i * 64 + p];
        }
        sg[o * 128 + p] = sigm(vy);
        sg[o * 128 + 64 + p] = sigm(vx);
    }
    __syncthreads();

    // P4: instance-norm stats
    if (t < 512) {
        const int i = t >> 6, l = t & 63, ys = l >> 3, xb = l & 7;
        const float4 sa = *reinterpret_cast<const float4*>(&sg[i * 128 + 64 + xb * 8]);
        const float4 sb = *reinterpret_cast<const float4*>(&sg[i * 128 + 64 + xb * 8 + 4]);
        float s = 0.f, s2 = 0.f;
#pragma unroll
        for (int r = 0; r < 8; ++r) {
            const float shv = sg[i * 128 + ys * 8 + r];
            const uint4 d = *reinterpret_cast<const uint4*>(
                &tile[i * CSTR + (ys * 8 + r) * 32 + xb * 4]);
            float g0 = blo(d.x) * shv * sa.x; s += g0; s2 += g0 * g0;
            float g1 = bhi(d.x) * shv * sa.y; s += g1; s2 += g1 * g1;
            float g2 = blo(d.y) * shv * sa.z; s += g2; s2 += g2 * g2;
            float g3 = bhi(d.y) * shv * sa.w; s += g3; s2 += g3 * g3;
            float g4 = blo(d.z) * shv * sb.x; s += g4; s2 += g4 * g4;
            float g5 = bhi(d.z) * shv * sb.y; s += g5; s2 += g5 * g5;
            float g6 = blo(d.w) * shv * sb.z; s += g6; s2 += g6 * g6;
            float g7 = bhi(d.w) * shv * sb.w; s += g7; s2 += g7 * g7;
        }
#pragma unroll
        for (int off = 32; off; off >>= 1) {
            s += __shfl_xor(s, off);
            s2 += __shfl_xor(s2, off);
        }
        if (l == 0) {
            float mu = s * (1.0f / 4096.0f);
            float var = s2 * (1.0f / 4096.0f) - mu * mu;
            float a = rsqrtf(var + 1e-5f) * gn_w[i];
            Ai[i] = a;
            Ci[i] = gn_b[i] - mu * a;
        }
    }
    // P5a: conv channel means via rectangle sums (wave 0)
    if (t < 64) {
        const int o = t >> 3, i = t & 7;
        const float T = Ti[i];
        float part = 0.f;
#pragma unroll
        for (int ky = 0; ky < 3; ++ky) {
            int dy = ky - 1;
#pragma unroll
            for (int kx = 0; kx < 3; ++kx) {
                int dx = kx - 1;
                float S = T;
                int er = (dy < 0) ? 63 : 0;
                int ec = (dx < 0) ? 63 : 0;
                if (dy != 0) S -= Rs[i * 64 + er];
                if (dx != 0) S -= Cs[i * 64 + ec];
                if (dy != 0 && dx != 0) {
                    uint u = tile[i * CSTR + er * 32 + (ec >> 1)];
                    S += (ec & 1) ? bhi(u) : blo(u);
                }
                part += w3[((o * 8 + i) * 3 + ky) * 3 + kx] * S;
            }
        }
        part += __shfl_xor(part, 1); part += __shfl_xor(part, 2); part += __shfl_xor(part, 4);
        if (i == 0) m2s[o] = part * (1.0f / 4096.0f) + b3[o];
    }
    // P5b: the two 8-way softmaxes (wave 0)
    if (t < 8) {
        float mx = m2s[0];
#pragma unroll
        for (int o = 1; o < 8; ++o) mx = fmaxf(mx, m2s[o]);
        float sum = 0.f;
#pragma unroll
        for (int o = 0; o < 8; ++o) sum += __expf(m2s[o] - mx);
        x21s[t] = __expf(m2s[t] - mx) / sum;
        // x1 spatial mean == gn_b exactly (normalized field)
        float mx1 = gn_b[0];
#pragma unroll
        for (int o = 1; o < 8; ++o) mx1 = fmaxf(mx1, gn_b[o]);
        float sum1 = 0.f;
#pragma unroll
        for (int o = 0; o < 8; ++o) sum1 += __expf(gn_b[o] - mx1);
        x11s[t] = __expf(gn_b[t] - mx1) / sum1;
    }
    __syncthreads();

    // P5c: collapsed filter (padded [8][12]), t1s, wconst
    if (t < 72) {
        const int i = t / 9, k = t % 9;
        float acc = 0.f;
#pragma unroll
        for (int o = 0; o < 8; ++o) acc += x11s[o] * w3[(o * 8 + i) * 9 + k];
        weff[i * 12 + (k / 3) * 4 + (k % 3)] = acc;
    }
    if (t < 512) {
        const int i = t >> 6, y = t & 63;
        t1s[i * 64 + y] = x21s[i] * Ai[i] * sg[i * 128 + y];
    }
    if (t == 0) {
        float wc = 0.f;
#pragma unroll
        for (int o = 0; o < 8; ++o) wc += x11s[o] * b3[o] + x21s[o] * Ci[o];
        *wconst = wc;
    }
}

// ---- apply phase: all 1024 threads, 4 px each ------------------------------
__device__ __forceinline__ void apply_phase(
    const int t, const uint* __restrict__ tile, const float* __restrict__ sg,
    const float* __restrict__ t1s, const float* __restrict__ weff,
    const float wconst, float4* __restrict__ out4)
{
    const int y = t >> 4, xq = t & 15;      // 4 consecutive px per thread
    float ws0 = wconst, ws1 = wconst, ws2 = wconst, ws3 = wconst;
    uint2 ctr[8];
#pragma unroll
    for (int i = 0; i < 8; ++i) {
        const float t1v = t1s[i * 64 + y];
        const float4 sa = *reinterpret_cast<const float4*>(&sg[i * 128 + 64 + xq * 4]);
#pragma unroll
        for (int dy = -1; dy <= 1; ++dy) {
            const int yy = y + dy;
            if (yy < 0 || yy > 63) continue;   // lanes at masked edges also mask shfl use
            const uint2 d = *reinterpret_cast<const uint2*>(
                &tile[i * CSTR + yy * 32 + xq * 2]);
            float f0 = blo(d.x), f1 = bhi(d.x), f2 = blo(d.y), f3 = bhi(d.y);
            float vm = __shfl_up(f3, 1);       // prev lane's last px (same row)
            float vp = __shfl_down(f0, 1);     // next lane's first px
            vm = (xq == 0) ? 0.f : vm;
            vp = (xq == 15) ? 0.f : vp;
            const float4 wv = *reinterpret_cast<const float4*>(&weff[i * 12 + (dy + 1) * 4]);
            ws0 += wv.x * vm + wv.y * f0 + wv.z * f1;
            ws1 += wv.x * f0 + wv.y * f1 + wv.z * f2;
            ws2 += wv.x * f1 + wv.y * f2 + wv.z * f3;
            ws3 += wv.x * f2 + wv.y * f3 + wv.z * vp;
            if (dy == 0) {
                ctr[i] = d;
                ws0 += t1v * sa.x * f0;
                ws1 += t1v * sa.y * f1;
                ws2 += t1v * sa.z * f2;
                ws3 += t1v * sa.w * f3;
            }
        }
    }
    const float s0 = sigm(ws0), s1 = sigm(ws1), s2 = sigm(ws2), s3 = sigm(ws3);
    const size_t p0 = (size_t)(y * 64 + xq * 4) * 64;
    float4 u, w;
    u.x = blo(ctr[0].x) * s0; u.y = blo(ctr[1].x) * s0; u.z = blo(ctr[2].x) * s0; u.w = blo(ctr[3].x) * s0;
    w.x = blo(ctr[4].x) * s0; w.y = blo(ctr[5].x) * s0; w.z = blo(ctr[6].x) * s0; w.w = blo(ctr[7].x) * s0;
    out4[p0 + 0] = u; out4[p0 + 1] = w;
    u.x = bhi(ctr[0].x) * s1; u.y = bhi(ctr[1].x) * s1; u.z = bhi(ctr[2].x) * s1; u.w = bhi(ctr[3].x) * s1;
    w.x = bhi(ctr[4].x) * s1; w.y = bhi(ctr[5].x) * s1; w.z = bhi(ctr[6].x) * s1; w.w = bhi(ctr[7].x) * s1;
    out4[p0 + 64] = u; out4[p0 + 65] = w;
    u.x = blo(ctr[0].y) * s2; u.y = blo(ctr[1].y) * s2; u.z = blo(ctr[2].y) * s2; u.w = blo(ctr[3].y) * s2;
    w.x = blo(ctr[4].y) * s2; w.y = blo(ctr[5].y) * s2; w.z = blo(ctr[6].y) * s2; w.w = blo(ctr[7].y) * s2;
    out4[p0 + 128] = u; out4[p0 + 129] = w;
    u.x = bhi(ctr[0].y) * s3; u.y = bhi(ctr[1].y) * s3; u.z = bhi(ctr[2].y) * s3; u.w = bhi(ctr[3].y) * s3;
    w.x = bhi(ctr[4].y) * s3; w.y = bhi(ctr[5].y) * s3; w.z = bhi(ctr[6].y) * s3; w.w = bhi(ctr[7].y) * s3;
    out4[p0 + 192] = u; out4[p0 + 193] = w;
}

__global__ __launch_bounds__(1024, 4) void fused_ema_pair_kernel(
    const float* __restrict__ x,     // (32, 4096, 256)
    const float* __restrict__ w1, const float* __restrict__ b1,
    const float* __restrict__ w3, const float* __restrict__ b3,
    const float* __restrict__ gn_w, const float* __restrict__ gn_b,
    float* __restrict__ out)
{
    __shared__ __align__(16) uint  gxp0[8 * CSTR];   // 65,664 B tile s0
    __shared__ __align__(16) uint  gxp1[8 * CSTR];   // 65,664 B tile s1
    __shared__ __align__(16) float sg0[1024], sg1[1024];
    __shared__ __align__(16) float uni[1024];        // Rs|Cs scratch (shared)
    __shared__ __align__(16) float t1s0[512], t1s1[512];
    __shared__ __align__(16) float weff0[96], weff1[96];
    __shared__ float Ti[8], m2s[8], Ai[8], Ci[8], x11s[8], x21s[8];
    __shared__ float wc0, wc1;

    const int t = threadIdx.x;
    const int bi = blockIdx.x;
    // pair p: quad members on same XCD at adjacent slots
    const int p = (bi & 7) * 64 + (bi >> 3);
    const int n0 = 2 * p;
    const int n1 = 2 * p + 1;
    const int b = n0 >> 5;
    const int g0 = n0 & 31, g1 = n1 & 31;

    const float4* x40 = reinterpret_cast<const float4*>(x) + (size_t)b * 4096 * 64 + g0 * 2;
    const float4* x41 = reinterpret_cast<const float4*>(x) + (size_t)b * 4096 * 64 + g1 * 2;
    float4* out40 = reinterpret_cast<float4*>(out) + (size_t)b * 4096 * 64 + g0 * 2;
    float4* out41 = reinterpret_cast<float4*>(out) + (size_t)b * 4096 * 64 + g1 * 2;

    // ---- P1(s0): load + pack -> tile0 -------------------------------------
    {
#pragma unroll
        for (int k = 0; k < 4; ++k) {
            int idx = k * 1024 + t;       // 0..4095
            int q = idx >> 1;             // pixel pair
            int half = idx & 1;
            float4 va = x40[(size_t)q * 128 + half];
            float4 vb = x40[(size_t)q * 128 + 64 + half];
            int ch = half * 4;
            gxp0[(ch + 0) * CSTR + q] = pk2(va.x, vb.x);
            gxp0[(ch + 1) * CSTR + q] = pk2(va.y, vb.y);
            gxp0[(ch + 2) * CSTR + q] = pk2(va.z, vb.z);
            gxp0[(ch + 3) * CSTR + q] = pk2(va.w, vb.w);
        }
    }
    __syncthreads();

    // ---- issue s1 global loads (registers; stay in flight across stats) ----
    float4 sva[4], svb[4];
#pragma unroll
    for (int k = 0; k < 4; ++k) {
        int idx = k * 1024 + t;
        int q = idx >> 1;
        int half = idx & 1;
        sva[k] = x41[(size_t)q * 128 + half];
        svb[k] = x41[(size_t)q * 128 + 64 + half];
    }
    __builtin_amdgcn_sched_barrier(0);     // pin issue point before stats

    // ---- stats(s0) (s1 reads in flight) ------------------------------------
    stats_phases(t, gxp0, sg0, t1s0, weff0, &wc0, uni,
                 Ti, m2s, Ai, Ci, x11s, x21s, w1, b1, w3, b3, gn_w, gn_b);
    __syncthreads();

    // ---- pack s1 -> tile1 ---------------------------------------------------
    {
#pragma unroll
        for (int k = 0; k < 4; ++k) {
            int idx = k * 1024 + t;
            int q = idx >> 1;
            int half = idx & 1;
            int ch = half * 4;
            gxp1[(ch + 0) * CSTR + q] = pk2(sva[k].x, svb[k].x);
            gxp1[(ch + 1) * CSTR + q] = pk2(sva[k].y, svb[k].y);
            gxp1[(ch + 2) * CSTR + q] = pk2(sva[k].z, svb[k].z);
            gxp1[(ch + 3) * CSTR + q] = pk2(sva[k].w, svb[k].w);
        }
    }
    __syncthreads();

    // ---- apply(s0): stores fire; no barrier after (disjoint LDS sets) ------
    apply_phase(t, gxp0, sg0, t1s0, weff0, wc0, out40);

    // ---- stats(s1) overlaps s0's store drain --------------------------------
    stats_phases(t, gxp1, sg1, t1s1, weff1, &wc1, uni,
                 Ti, m2s, Ai, Ci, x11s, x21s, w1, b1, w3, b3, gn_w, gn_b);
    __syncthreads();

    // ---- apply(s1) ----------------------------------------------------------
    apply_phase(t, gxp1, sg1, t1s1, weff1, wc1, out41);
}

extern "C" void kernel_launch(void* const* d_in, const int* in_sizes, int n_in,
                              void* d_out, int out_size, void* d_ws, size_t ws_size,
                              hipStream_t stream) {
    const float* x    = (const float*)d_in[0];
    const float* w1   = (const float*)d_in[1];
    const float* b1   = (const float*)d_in[2];
    const float* w3   = (const float*)d_in[3];
    const float* b3   = (const float*)d_in[4];
    const float* gn_w = (const float*)d_in[5];
    const float* gn_b = (const float*)d_in[6];
    float* out = (float*)d_out;

    hipLaunchKernelGGL(fused_ema_pair_kernel, dim3(NBLK), dim3(NTHR), 0, stream,
                       x, w1, b1, w3, b3, gn_w, gn_b, out);
}